// Round 8
// baseline (4609.258 us; speedup 1.0000x reference)
//
#include <hip/hip_runtime.h>
#include <math.h>

// ---------------- problem constants ----------------
#define NB    8
#define NPTS  100000
#define NCLS  18
#define ND    128
#define KFPS  2048
#define KTOP  256

// ---------------- FPS config ----------------
#define FWGS       32                 // workgroups per batch
#define FTHR       256                // threads per WG
#define FBTHREADS  (FWGS*FTHR)        // 8192 threads per batch
#define PPT        13                 // points per thread (13*8192 >= 100000)
#define NSLOT      32                 // one record per WG per batch
#define RSTRIDE    64                 // u64s per agent record slot (512 B)
#define TAG_SHIFT  49
#define KEY_MASK   ((1ull<<TAG_SHIFT)-1)
#define IDX_MASK   0x1FFFFull
#define INVALID_REC (~0ull)           // tag 0x7FFF: never matches live tags (1..2047)

// per-batch u64 region: [0,4096) agent banks (2x32x64) | [4096,4160) L2 banks (2x32) | pad
#define B_AGENT    0
#define B_L2       4096
#define B_TOTAL    4608
#define INIT_U64   4160                         // clear agent + L2 banks per batch
#define PART_U64   (NB * B_TOTAL)               // 36864 u64 = 288 KB

static_assert(PPT * FBTHREADS >= NPTS, "coverage");

// ---------------- out layout (float elements), total 2367488 ----------------
#define OUT_PTS    0          // 8*256*3    = 6144
#define OUT_FEATS  6144       // 8*256*128  = 262144
#define OUT_INDS   268288     // 8*256      = 2048
#define OUT_CROSS  270336     // 8*2048*128 = 2097152
// scratch INSIDE region 3 (overwritten by k_gather at the end):
#define OUT_SCORES OUT_CROSS              // 800000 floats
#define OUT_PART   (OUT_CROSS + 800000)   // 8B-aligned
static_assert((OUT_PART % 2) == 0, "u64 alignment");
static_assert(OUT_PART + PART_U64 * 2 <= OUT_CROSS + 2097152, "fits in region 3");

// ---------------- ws layout (bytes) — proven-safe 90112 ----------------
#define WS_CROSS    16384                   // NB*KFPS*4 = 65536
#define WS_SORTI    (16384+65536)           // NB*KTOP*4 = 8192   (end 90112)

// ---------------- sc0 (XCD-L2 coherence point) helpers ----------------
__device__ __forceinline__ unsigned long long ld_l2(const unsigned long long* p) {
  unsigned long long r;
  asm volatile("global_load_dwordx2 %0, %1, off sc0\n\ts_waitcnt vmcnt(0)"
               : "=&v"(r) : "v"((unsigned long long)p) : "memory");
  return r;
}
__device__ __forceinline__ void st_l2(unsigned long long* p, unsigned long long v) {
  asm volatile("global_store_dwordx2 %0, %1, off sc0"
               :: "v"((unsigned long long)p), "v"(v) : "memory");
}

// ============================================================
// Kernel 0: init record slots (runs before k_fps every call)
// ============================================================
__global__ void k_init(unsigned long long* __restrict__ partials) {
  int id = blockIdx.x * 256 + threadIdx.x;
  int bb = id / INIT_U64, off = id - bb * INIT_U64;
  if (bb < NB)
    __hip_atomic_store(&partials[(size_t)bb * B_TOTAL + off], INVALID_REC,
                       __ATOMIC_RELAXED, __HIP_MEMORY_SCOPE_AGENT);
}

// ============================================================
// Kernel 1: max_scores = sigmoid(max_c cls) * sigmoid(centerness)
// ============================================================
__global__ void k_scores(const float* __restrict__ cent,
                         const float* __restrict__ cls,
                         float* __restrict__ scores) {
  int gid = blockIdx.x * blockDim.x + threadIdx.x;
  if (gid >= NB * NPTS) return;
  const float* c = cls + (size_t)gid * NCLS;
  float m = c[0];
  #pragma unroll
  for (int i = 1; i < NCLS; ++i) m = fmaxf(m, c[i]);
  double sm = 1.0 / (1.0 + exp(-(double)m));
  double sc = 1.0 / (1.0 + exp(-(double)cent[gid]));
  scores[gid] = __fmul_rn((float)sm, (float)sc);
}

// ============================================================
// Kernel 2: per-batch exact top-256 (value desc, idx asc), output sorted idx
// ============================================================
__global__ __launch_bounds__(1024) void k_topk(const float* __restrict__ scores,
                                               int* __restrict__ sorti_ws,
                                               float* __restrict__ out_inds) {
  __shared__ unsigned hist[2048];
  __shared__ int candG[256];
  __shared__ int candE[512];
  __shared__ unsigned s_cg, s_ce, s_bin, s_rank;

  int b = blockIdx.x;
  int tid = threadIdx.x;
  const float* sb = scores + (size_t)b * NPTS;

  unsigned prefix = 0, pmask = 0;
  int r = KTOP;
  for (int pass = 0; pass < 3; ++pass) {
    int shift = (pass == 0) ? 21 : (pass == 1) ? 10 : 0;
    int bins  = (pass < 2) ? 2048 : 1024;
    for (int i = tid; i < bins; i += 1024) hist[i] = 0;
    __syncthreads();
    for (int n = tid; n < NPTS; n += 1024) {
      unsigned k = __float_as_uint(sb[n]);
      if ((k & pmask) == prefix) atomicAdd(&hist[(k >> shift) & (bins - 1)], 1u);
    }
    __syncthreads();
    if (tid == 0) {
      unsigned c = 0; int bin = bins - 1;
      for (; bin > 0; --bin) { unsigned h = hist[bin]; if (c + h >= (unsigned)r) break; c += h; }
      s_bin = (unsigned)bin; s_rank = (unsigned)r - c;
    }
    __syncthreads();
    prefix |= s_bin << shift;
    pmask  |= (unsigned)(bins - 1) << shift;
    r = (int)s_rank;
    __syncthreads();
  }
  unsigned T = prefix;
  int need = r;
  int nG = KTOP - need;

  if (tid == 0) { s_cg = 0; s_ce = 0; }
  __syncthreads();
  for (int n = tid; n < NPTS; n += 1024) {
    unsigned k = __float_as_uint(sb[n]);
    if (k > T)       { unsigned p = atomicAdd(&s_cg, 1u); if (p < 256) candG[p] = n; }
    else if (k == T) { unsigned p = atomicAdd(&s_ce, 1u); if (p < 512) candE[p] = n; }
  }
  __syncthreads();
  unsigned ce = s_ce;
  for (int i = tid; i < 512; i += 1024) if (i >= (int)ce) candE[i] = 0x7FFFFFFF;
  __syncthreads();
  for (int k2 = 2; k2 <= 512; k2 <<= 1)
    for (int j = k2 >> 1; j >= 1; j >>= 1) {
      if (tid < 512) {
        int i = tid, p = i ^ j;
        if (p > i) {
          int a = candE[i], bb = candE[p];
          bool up = ((i & k2) == 0);
          if ((a > bb) == up) { candE[i] = bb; candE[p] = a; }
        }
      }
      __syncthreads();
    }
  int* arr = (int*)hist;
  if (tid < KTOP) arr[tid] = (tid < nG) ? candG[tid] : candE[tid - nG];
  __syncthreads();
  for (int k2 = 2; k2 <= 256; k2 <<= 1)
    for (int j = k2 >> 1; j >= 1; j >>= 1) {
      if (tid < 256) {
        int i = tid, p = i ^ j;
        if (p > i) {
          int a = arr[i], bb = arr[p];
          bool up = ((i & k2) == 0);
          if ((a > bb) == up) { arr[i] = bb; arr[p] = a; }
        }
      }
      __syncthreads();
    }
  if (tid < KTOP) {
    sorti_ws[b * KTOP + tid] = arr[tid];
    out_inds[b * KTOP + tid] = (float)arr[tid];
  }
}

// ============================================================
// Kernel 3: FPS. Dual-publish consensus: every WG's record goes to BOTH
// a compact sc0/L2 slot (fast path, works iff batch co-XCD) and the
// round-5-proven agent-scope strided slot (always works). Pollers try L2
// briefly, then fall back to the agent loop. No cross-WG mode agreement
// exists anywhere. Ping-pong banks, tags t+1, bounded spins, clamped idx.
// ============================================================
__global__ __launch_bounds__(FTHR, 1) void k_fps(const float* __restrict__ points,
                                                 unsigned long long* __restrict__ partials,
                                                 int* __restrict__ cross_inds) {
  int b    = blockIdx.x & 7;     // if round-robin XCD mapping holds, batch = one XCD
  int wg   = blockIdx.x >> 3;    // 0..31
  int tid  = threadIdx.x;
  int lane = tid & 63;
  int wave = tid >> 6;           // 0..3
  int gthr = wg * FTHR + tid;

  __shared__ unsigned long long lred[4];
  __shared__ int lwin;

  const float* pb = points + (size_t)b * NPTS * 3;
  unsigned long long* base   = partials + (size_t)b * B_TOTAL;
  unsigned long long* agentB = base + B_AGENT;   // 2 banks x 32 slots x 512B stride
  unsigned long long* l2B    = base + B_L2;      // 2 banks x 32 slots, contiguous

  float px[PPT], py[PPT], pz[PPT], dd[PPT];
  #pragma unroll
  for (int i = 0; i < PPT; ++i) {
    int n = gthr + i * FBTHREADS;
    bool v = (n < NPTS);
    px[i] = v ? pb[3 * n + 0] : 0.f;
    py[i] = v ? pb[3 * n + 1] : 0.f;
    pz[i] = v ? pb[3 * n + 2] : 0.f;
    dd[i] = 1e10f;
  }
  if (wg == 0 && tid == 0) cross_inds[b * KFPS] = 0;

  int l2budget = 3;              // per-WG private; any mix of paths is correct
  int w = 0;
  for (int t = 0; t < KFPS - 1; ++t) {
    float wx = pb[3 * w + 0];
    float wy = pb[3 * w + 1];
    float wz = pb[3 * w + 2];

    // exact f32 update: d = ((dx*dx + dy*dy) + dz*dz), dist = min(dist, d)
    float bestv = -1.f; int besti = 0x1FFFF;
    #pragma unroll
    for (int i = 0; i < PPT; ++i) {
      int n = gthr + i * FBTHREADS;
      float dx = __fsub_rn(px[i], wx);
      float dy = __fsub_rn(py[i], wy);
      float dz = __fsub_rn(pz[i], wz);
      float s  = __fadd_rn(__fadd_rn(__fmul_rn(dx, dx), __fmul_rn(dy, dy)), __fmul_rn(dz, dz));
      float nd = fminf(dd[i], s);
      dd[i] = nd;
      bool upd = (n < NPTS) && (nd > bestv);   // strict > keeps lowest index on ties
      bestv = upd ? nd : bestv;
      besti = upd ? n : besti;
    }
    unsigned long long key = (bestv >= 0.f)
      ? (((unsigned long long)__float_as_uint(bestv) << 17) |
         (unsigned long long)(0x1FFFFu ^ (unsigned)besti))
      : 0ull;
    #pragma unroll
    for (int off = 32; off >= 1; off >>= 1) {
      unsigned long long o = __shfl_xor(key, off);
      if (o > key) key = o;
    }
    if (lane == 0) lred[wave] = key;
    __syncthreads();

    unsigned tag = (unsigned)t + 1u;
    if (wave == 0) {
      unsigned long long* abank = agentB + (size_t)(t & 1) * NSLOT * RSTRIDE;
      unsigned long long* lbank = l2B    + (size_t)(t & 1) * NSLOT;
      unsigned long long rec = 0;
      if (lane == 0) {
        unsigned long long k0 = lred[0], k1 = lred[1], k2 = lred[2], k3 = lred[3];
        if (k1 > k0) k0 = k1;
        if (k3 > k2) k2 = k3;
        if (k2 > k0) k0 = k2;
        rec = ((unsigned long long)tag << TAG_SHIFT) | k0;
        st_l2(&lbank[wg], rec);                              // fast-path copy
        __hip_atomic_store(&abank[(size_t)wg * RSTRIDE], rec,
                           __ATOMIC_RELAXED, __HIP_MEMORY_SCOPE_AGENT);  // proven path
      }

      unsigned long long r = 0;
      bool resolved = false;
      // ---- opportunistic L2 fast path (co-XCD case) ----
      if (l2budget > 0) {
        for (int tr = 0; tr < 6 && !resolved; ++tr) {
          if (lane < 32) r = ld_l2(&lbank[lane]);
          bool ok = (lane >= 32) || ((unsigned)(r >> TAG_SHIFT) == tag);
          resolved = (bool)__all((int)ok);
        }
        if (!resolved) --l2budget;   // strike; after 3 strikes skip L2 tries
      }
      // ---- terminal fallback: round-5-proven agent poll ----
      if (!resolved) {
        unsigned long long* addr = abank + (size_t)(lane & 31) * RSTRIDE;
        int spins = 0;
        for (;;) {
          if (lane < 32)
            r = __hip_atomic_load(addr, __ATOMIC_RELAXED, __HIP_MEMORY_SCOPE_AGENT);
          bool ok = (lane >= 32) || ((unsigned)(r >> TAG_SHIFT) == tag);
          if (__all((int)ok)) break;
          if (++spins > (1 << 14)) break;      // bounded: clamped result, never hangs
          if ((spins & 511) == 0 && lane == 0) {  // heal lost stores
            st_l2(&lbank[wg], rec);
            __hip_atomic_store(&abank[(size_t)wg * RSTRIDE], rec,
                               __ATOMIC_RELAXED, __HIP_MEMORY_SCOPE_AGENT);
          }
          __builtin_amdgcn_s_sleep(1);
        }
      }
      unsigned long long kk = (lane < 32) ? (r & KEY_MASK) : 0ull;
      #pragma unroll
      for (int off = 32; off >= 1; off >>= 1) {
        unsigned long long o = __shfl_xor(kk, off);
        if (o > kk) kk = o;
      }
      int ww = (int)(0x1FFFFu ^ (unsigned)(kk & IDX_MASK));
      if (ww >= NPTS) ww = 0;                  // safety: never OOB
      if (lane == 0) lwin = ww;
    }
    __syncthreads();
    w = lwin;
    if (wg == 0 && tid == 0) cross_inds[b * KFPS + t + 1] = w;
  }
}

// ============================================================
// Kernel 4: gathers (feats_sel, pts_sel, cross_features)
// ============================================================
#define GF4 ((NB * (KTOP + KFPS)) * (ND / 4))   // 589824 float4 gathers
#define GPTS (NB * KTOP * 3)                    // 6144

__global__ void k_gather(const float* __restrict__ pts,
                         const float* __restrict__ feat,
                         const int* __restrict__ sorti,
                         const int* __restrict__ crossi,
                         float* __restrict__ out) {
  int id = blockIdx.x * 256 + threadIdx.x;
  if (id < GF4) {
    int row = id >> 5, c4 = id & 31;
    int b, s; float* dst;
    if (row < NB * KTOP) {
      b = row >> 8;
      s = sorti[row];
      dst = out + OUT_FEATS + (size_t)row * ND;
    } else {
      int r2 = row - NB * KTOP;
      b = r2 >> 11;
      s = crossi[r2];
      dst = out + OUT_CROSS + (size_t)r2 * ND;
    }
    if (s < 0 || s >= NPTS) s = 0;
    float4 v = ((const float4*)(feat + ((size_t)b * NPTS + (size_t)s) * ND))[c4];
    ((float4*)dst)[c4] = v;
  } else if (id < GF4 + GPTS) {
    int q = id - GF4;
    int row = q / 3, d = q - row * 3;
    int b = row >> 8;
    int s = sorti[row];
    if (s < 0 || s >= NPTS) s = 0;
    out[OUT_PTS + q] = pts[((size_t)b * NPTS + (size_t)s) * 3 + d];
  }
}

// ============================================================
extern "C" void kernel_launch(void* const* d_in, const int* in_sizes, int n_in,
                              void* d_out, int out_size, void* d_ws, size_t ws_size,
                              hipStream_t stream) {
  const float* cent = (const float*)d_in[0];
  const float* cls  = (const float*)d_in[1];
  const float* pts  = (const float*)d_in[2];
  const float* feat = (const float*)d_in[3];
  float* out = (float*)d_out;

  unsigned long long* partials = (unsigned long long*)(out + OUT_PART);
  int* cross_ws = (int*)((char*)d_ws + WS_CROSS);
  int* sorti_ws = (int*)((char*)d_ws + WS_SORTI);
  float* scores = out + OUT_SCORES;

  hipLaunchKernelGGL(k_init, dim3((NB * INIT_U64 + 255) / 256), dim3(256), 0, stream,
                     partials);
  hipLaunchKernelGGL(k_scores, dim3((NB * NPTS + 255) / 256), dim3(256), 0, stream,
                     cent, cls, scores);
  hipLaunchKernelGGL(k_topk, dim3(NB), dim3(1024), 0, stream,
                     scores, sorti_ws, out + OUT_INDS);
  hipLaunchKernelGGL(k_fps, dim3(NB * FWGS), dim3(FTHR), 0, stream,
                     pts, partials, cross_ws);
  int gtot = GF4 + GPTS;
  hipLaunchKernelGGL(k_gather, dim3((gtot + 255) / 256), dim3(256), 0, stream,
                     pts, feat, sorti_ws, cross_ws, out);
}

// Round 9
// 4378.238 us; speedup vs baseline: 1.0528x; 1.0528x over previous
//
#include <hip/hip_runtime.h>
#include <math.h>

// ---------------- problem constants ----------------
#define NB    8
#define NPTS  100000
#define NCLS  18
#define ND    128
#define KFPS  2048
#define KTOP  256

// ---------------- FPS config ----------------
#define FWGS       32                 // workgroups per batch
#define FTHR       256                // threads per WG
#define FBTHREADS  (FWGS*FTHR)        // 8192 threads per batch
#define PPT        13                 // points per thread (13*8192 >= 100000)
#define NSLOT      32                 // one record per WG per batch
#define RSTRIDE    64                 // u64s per agent record slot (512 B)
#define TAG_SHIFT  49
#define KEY_MASK   ((1ull<<TAG_SHIFT)-1)
#define IDX_MASK   0x1FFFFull
#define INVALID_REC (~0ull)           // tag 0x7FFF: never matches live tags (1..2047)

// per-batch u64 region: [0,4096) agent banks (2x32x64) | [4096,4160) L2 banks (2x32) | pad
#define B_AGENT    0
#define B_L2       4096
#define B_TOTAL    4608
#define INIT_U64   4160                         // clear agent + L2 banks per batch
#define PART_U64   (NB * B_TOTAL)               // 36864 u64 = 288 KB

static_assert(PPT * FBTHREADS >= NPTS, "coverage");

// ---------------- out layout (float elements), total 2367488 ----------------
#define OUT_PTS    0          // 8*256*3    = 6144
#define OUT_FEATS  6144       // 8*256*128  = 262144
#define OUT_INDS   268288     // 8*256      = 2048
#define OUT_CROSS  270336     // 8*2048*128 = 2097152
// scratch INSIDE region 3 (overwritten by k_gather at the end):
#define OUT_SCORES OUT_CROSS              // 800000 floats
#define OUT_PART   (OUT_CROSS + 800000)   // 8B-aligned
static_assert((OUT_PART % 2) == 0, "u64 alignment");
static_assert(OUT_PART + PART_U64 * 2 <= OUT_CROSS + 2097152, "fits in region 3");

// ---------------- ws layout (bytes) — proven-safe 90112 ----------------
#define WS_CROSS    16384                   // NB*KFPS*4 = 65536
#define WS_SORTI    (16384+65536)           // NB*KTOP*4 = 8192   (end 90112)

// ---------------- sc0 (XCD-L2 coherence point) helpers ----------------
__device__ __forceinline__ unsigned long long ld_l2(const unsigned long long* p) {
  unsigned long long r;
  asm volatile("global_load_dwordx2 %0, %1, off sc0\n\ts_waitcnt vmcnt(0)"
               : "=&v"(r) : "v"((unsigned long long)p) : "memory");
  return r;
}
__device__ __forceinline__ void st_l2(unsigned long long* p, unsigned long long v) {
  asm volatile("global_store_dwordx2 %0, %1, off sc0"
               :: "v"((unsigned long long)p), "v"(v) : "memory");
}

// ============================================================
// Kernel 0: init record slots (runs before k_fps every call)
// ============================================================
__global__ void k_init(unsigned long long* __restrict__ partials) {
  int id = blockIdx.x * 256 + threadIdx.x;
  int bb = id / INIT_U64, off = id - bb * INIT_U64;
  if (bb < NB)
    __hip_atomic_store(&partials[(size_t)bb * B_TOTAL + off], INVALID_REC,
                       __ATOMIC_RELAXED, __HIP_MEMORY_SCOPE_AGENT);
}

// ============================================================
// Kernel 1: max_scores = sigmoid(max_c cls) * sigmoid(centerness)
// ============================================================
__global__ void k_scores(const float* __restrict__ cent,
                         const float* __restrict__ cls,
                         float* __restrict__ scores) {
  int gid = blockIdx.x * blockDim.x + threadIdx.x;
  if (gid >= NB * NPTS) return;
  const float* c = cls + (size_t)gid * NCLS;
  float m = c[0];
  #pragma unroll
  for (int i = 1; i < NCLS; ++i) m = fmaxf(m, c[i]);
  double sm = 1.0 / (1.0 + exp(-(double)m));
  double sc = 1.0 / (1.0 + exp(-(double)cent[gid]));
  scores[gid] = __fmul_rn((float)sm, (float)sc);
}

// ============================================================
// Kernel 2: per-batch exact top-256 (value desc, idx asc), output sorted idx
// ============================================================
__global__ __launch_bounds__(1024) void k_topk(const float* __restrict__ scores,
                                               int* __restrict__ sorti_ws,
                                               float* __restrict__ out_inds) {
  __shared__ unsigned hist[2048];
  __shared__ int candG[256];
  __shared__ int candE[512];
  __shared__ unsigned s_cg, s_ce, s_bin, s_rank;

  int b = blockIdx.x;
  int tid = threadIdx.x;
  const float* sb = scores + (size_t)b * NPTS;

  unsigned prefix = 0, pmask = 0;
  int r = KTOP;
  for (int pass = 0; pass < 3; ++pass) {
    int shift = (pass == 0) ? 21 : (pass == 1) ? 10 : 0;
    int bins  = (pass < 2) ? 2048 : 1024;
    for (int i = tid; i < bins; i += 1024) hist[i] = 0;
    __syncthreads();
    for (int n = tid; n < NPTS; n += 1024) {
      unsigned k = __float_as_uint(sb[n]);
      if ((k & pmask) == prefix) atomicAdd(&hist[(k >> shift) & (bins - 1)], 1u);
    }
    __syncthreads();
    if (tid == 0) {
      unsigned c = 0; int bin = bins - 1;
      for (; bin > 0; --bin) { unsigned h = hist[bin]; if (c + h >= (unsigned)r) break; c += h; }
      s_bin = (unsigned)bin; s_rank = (unsigned)r - c;
    }
    __syncthreads();
    prefix |= s_bin << shift;
    pmask  |= (unsigned)(bins - 1) << shift;
    r = (int)s_rank;
    __syncthreads();
  }
  unsigned T = prefix;
  int need = r;
  int nG = KTOP - need;

  if (tid == 0) { s_cg = 0; s_ce = 0; }
  __syncthreads();
  for (int n = tid; n < NPTS; n += 1024) {
    unsigned k = __float_as_uint(sb[n]);
    if (k > T)       { unsigned p = atomicAdd(&s_cg, 1u); if (p < 256) candG[p] = n; }
    else if (k == T) { unsigned p = atomicAdd(&s_ce, 1u); if (p < 512) candE[p] = n; }
  }
  __syncthreads();
  unsigned ce = s_ce;
  for (int i = tid; i < 512; i += 1024) if (i >= (int)ce) candE[i] = 0x7FFFFFFF;
  __syncthreads();
  for (int k2 = 2; k2 <= 512; k2 <<= 1)
    for (int j = k2 >> 1; j >= 1; j >>= 1) {
      if (tid < 512) {
        int i = tid, p = i ^ j;
        if (p > i) {
          int a = candE[i], bb = candE[p];
          bool up = ((i & k2) == 0);
          if ((a > bb) == up) { candE[i] = bb; candE[p] = a; }
        }
      }
      __syncthreads();
    }
  int* arr = (int*)hist;
  if (tid < KTOP) arr[tid] = (tid < nG) ? candG[tid] : candE[tid - nG];
  __syncthreads();
  for (int k2 = 2; k2 <= 256; k2 <<= 1)
    for (int j = k2 >> 1; j >= 1; j >>= 1) {
      if (tid < 256) {
        int i = tid, p = i ^ j;
        if (p > i) {
          int a = arr[i], bb = arr[p];
          bool up = ((i & k2) == 0);
          if ((a > bb) == up) { arr[i] = bb; arr[p] = a; }
        }
      }
      __syncthreads();
    }
  if (tid < KTOP) {
    sorti_ws[b * KTOP + tid] = arr[tid];
    out_inds[b * KTOP + tid] = (float)arr[tid];
  }
}

// ============================================================
// Kernel 3: FPS. Dual-publish (sc0/L2 slot + agent-scope slot). Pollers
// interleave: every iteration a cheap L2 sweep; every 3rd iteration also
// the proven agent sweep. No budgets/strikes/mode agreement — whichever
// source first shows all 32 tags wins (records are bit-identical).
// Ping-pong banks, tags t+1, bounded spins, clamped idx.
// ============================================================
__global__ __launch_bounds__(FTHR, 1) void k_fps(const float* __restrict__ points,
                                                 unsigned long long* __restrict__ partials,
                                                 int* __restrict__ cross_inds) {
  int b    = blockIdx.x & 7;     // measured round-robin: blockIdx%8 = XCD (m09)
  int wg   = blockIdx.x >> 3;    // 0..31
  int tid  = threadIdx.x;
  int lane = tid & 63;
  int wave = tid >> 6;           // 0..3
  int gthr = wg * FTHR + tid;

  __shared__ unsigned long long lred[4];
  __shared__ int lwin;

  const float* pb = points + (size_t)b * NPTS * 3;
  unsigned long long* base   = partials + (size_t)b * B_TOTAL;
  unsigned long long* agentB = base + B_AGENT;   // 2 banks x 32 slots x 512B stride
  unsigned long long* l2B    = base + B_L2;      // 2 banks x 32 slots, contiguous

  float px[PPT], py[PPT], pz[PPT], dd[PPT];
  #pragma unroll
  for (int i = 0; i < PPT; ++i) {
    int n = gthr + i * FBTHREADS;
    bool v = (n < NPTS);
    px[i] = v ? pb[3 * n + 0] : 0.f;
    py[i] = v ? pb[3 * n + 1] : 0.f;
    pz[i] = v ? pb[3 * n + 2] : 0.f;
    // pin in registers: prevent the compiler from rematerializing these as
    // per-round global reloads (round-8 evidence: VGPR_Count=48 < 52 needed)
    asm volatile("" : "+v"(px[i]), "+v"(py[i]), "+v"(pz[i]));
    dd[i] = 1e10f;
  }
  if (wg == 0 && tid == 0) cross_inds[b * KFPS] = 0;

  int w = 0;
  for (int t = 0; t < KFPS - 1; ++t) {
    float wx = pb[3 * w + 0];
    float wy = pb[3 * w + 1];
    float wz = pb[3 * w + 2];

    // exact f32 update: d = ((dx*dx + dy*dy) + dz*dz), dist = min(dist, d)
    float bestv = -1.f; int besti = 0x1FFFF;
    #pragma unroll
    for (int i = 0; i < PPT; ++i) {
      int n = gthr + i * FBTHREADS;
      float dx = __fsub_rn(px[i], wx);
      float dy = __fsub_rn(py[i], wy);
      float dz = __fsub_rn(pz[i], wz);
      float s  = __fadd_rn(__fadd_rn(__fmul_rn(dx, dx), __fmul_rn(dy, dy)), __fmul_rn(dz, dz));
      float nd = fminf(dd[i], s);
      dd[i] = nd;
      bool upd = (n < NPTS) && (nd > bestv);   // strict > keeps lowest index on ties
      bestv = upd ? nd : bestv;
      besti = upd ? n : besti;
    }
    unsigned long long key = (bestv >= 0.f)
      ? (((unsigned long long)__float_as_uint(bestv) << 17) |
         (unsigned long long)(0x1FFFFu ^ (unsigned)besti))
      : 0ull;
    #pragma unroll
    for (int off = 32; off >= 1; off >>= 1) {
      unsigned long long o = __shfl_xor(key, off);
      if (o > key) key = o;
    }
    if (lane == 0) lred[wave] = key;
    __syncthreads();

    unsigned tag = (unsigned)t + 1u;
    if (wave == 0) {
      unsigned long long* abank = agentB + (size_t)(t & 1) * NSLOT * RSTRIDE;
      unsigned long long* lbank = l2B    + (size_t)(t & 1) * NSLOT;
      unsigned long long rec = 0;
      if (lane == 0) {
        unsigned long long k0 = lred[0], k1 = lred[1], k2 = lred[2], k3 = lred[3];
        if (k1 > k0) k0 = k1;
        if (k3 > k2) k2 = k3;
        if (k2 > k0) k0 = k2;
        rec = ((unsigned long long)tag << TAG_SHIFT) | k0;
        st_l2(&lbank[wg], rec);                              // fast path first
        __hip_atomic_store(&abank[(size_t)wg * RSTRIDE], rec,
                           __ATOMIC_RELAXED, __HIP_MEMORY_SCOPE_AGENT);  // proven path
      }

      unsigned long long r = 0;
      int it = 0, spins = 0;
      for (;;) {
        // ---- cheap XCD-local L2 sweep (every iteration) ----
        if (lane < 32) r = ld_l2(&lbank[lane]);
        bool ok = (lane >= 32) || ((unsigned)(r >> TAG_SHIFT) == tag);
        if (__all((int)ok)) break;
        // ---- proven agent sweep (every 3rd iteration) ----
        if ((++it % 3) == 0) {
          if (lane < 32)
            r = __hip_atomic_load(&abank[(size_t)(lane & 31) * RSTRIDE],
                                  __ATOMIC_RELAXED, __HIP_MEMORY_SCOPE_AGENT);
          ok = (lane >= 32) || ((unsigned)(r >> TAG_SHIFT) == tag);
          if (__all((int)ok)) break;
          if (++spins > (1 << 14)) break;      // bounded: clamped result, never hangs
          if ((spins & 511) == 0 && lane == 0) {  // heal lost stores
            st_l2(&lbank[wg], rec);
            __hip_atomic_store(&abank[(size_t)wg * RSTRIDE], rec,
                               __ATOMIC_RELAXED, __HIP_MEMORY_SCOPE_AGENT);
          }
          __builtin_amdgcn_s_sleep(1);
        }
      }
      unsigned long long kk = (lane < 32) ? (r & KEY_MASK) : 0ull;
      #pragma unroll
      for (int off = 32; off >= 1; off >>= 1) {
        unsigned long long o = __shfl_xor(kk, off);
        if (o > kk) kk = o;
      }
      int ww = (int)(0x1FFFFu ^ (unsigned)(kk & IDX_MASK));
      if (ww >= NPTS) ww = 0;                  // safety: never OOB
      if (lane == 0) lwin = ww;
    }
    __syncthreads();
    w = lwin;
    if (wg == 0 && tid == 0) cross_inds[b * KFPS + t + 1] = w;
  }
}

// ============================================================
// Kernel 4: gathers (feats_sel, pts_sel, cross_features)
// ============================================================
#define GF4 ((NB * (KTOP + KFPS)) * (ND / 4))   // 589824 float4 gathers
#define GPTS (NB * KTOP * 3)                    // 6144

__global__ void k_gather(const float* __restrict__ pts,
                         const float* __restrict__ feat,
                         const int* __restrict__ sorti,
                         const int* __restrict__ crossi,
                         float* __restrict__ out) {
  int id = blockIdx.x * 256 + threadIdx.x;
  if (id < GF4) {
    int row = id >> 5, c4 = id & 31;
    int b, s; float* dst;
    if (row < NB * KTOP) {
      b = row >> 8;
      s = sorti[row];
      dst = out + OUT_FEATS + (size_t)row * ND;
    } else {
      int r2 = row - NB * KTOP;
      b = r2 >> 11;
      s = crossi[r2];
      dst = out + OUT_CROSS + (size_t)r2 * ND;
    }
    if (s < 0 || s >= NPTS) s = 0;
    float4 v = ((const float4*)(feat + ((size_t)b * NPTS + (size_t)s) * ND))[c4];
    ((float4*)dst)[c4] = v;
  } else if (id < GF4 + GPTS) {
    int q = id - GF4;
    int row = q / 3, d = q - row * 3;
    int b = row >> 8;
    int s = sorti[row];
    if (s < 0 || s >= NPTS) s = 0;
    out[OUT_PTS + q] = pts[((size_t)b * NPTS + (size_t)s) * 3 + d];
  }
}

// ============================================================
extern "C" void kernel_launch(void* const* d_in, const int* in_sizes, int n_in,
                              void* d_out, int out_size, void* d_ws, size_t ws_size,
                              hipStream_t stream) {
  const float* cent = (const float*)d_in[0];
  const float* cls  = (const float*)d_in[1];
  const float* pts  = (const float*)d_in[2];
  const float* feat = (const float*)d_in[3];
  float* out = (float*)d_out;

  unsigned long long* partials = (unsigned long long*)(out + OUT_PART);
  int* cross_ws = (int*)((char*)d_ws + WS_CROSS);
  int* sorti_ws = (int*)((char*)d_ws + WS_SORTI);
  float* scores = out + OUT_SCORES;

  hipLaunchKernelGGL(k_init, dim3((NB * INIT_U64 + 255) / 256), dim3(256), 0, stream,
                     partials);
  hipLaunchKernelGGL(k_scores, dim3((NB * NPTS + 255) / 256), dim3(256), 0, stream,
                     cent, cls, scores);
  hipLaunchKernelGGL(k_topk, dim3(NB), dim3(1024), 0, stream,
                     scores, sorti_ws, out + OUT_INDS);
  hipLaunchKernelGGL(k_fps, dim3(NB * FWGS), dim3(FTHR), 0, stream,
                     pts, partials, cross_ws);
  int gtot = GF4 + GPTS;
  hipLaunchKernelGGL(k_gather, dim3((gtot + 255) / 256), dim3(256), 0, stream,
                     pts, feat, sorti_ws, cross_ws, out);
}